// Round 1
// baseline (208.260 us; speedup 1.0000x reference)
//
#include <hip/hip_runtime.h>
#include <math.h>

#define TAU_F 0.02f
#define NB 64
#define NQ 32
#define NS 256
#define ND 128
#define MAXT 20
#define PERMSTRIDE 320

typedef __bf16 bf16x8 __attribute__((ext_vector_type(8)));
typedef float f32x4 __attribute__((ext_vector_type(4)));

// workspace layout (bytes)
#define OFF_PERM    0u          // 64*320*4   = 81920
#define OFF_TILEMOD 81920u      // 64*20*4    = 5120
#define OFF_TCOUNT  87040u      // 64*4
#define OFF_QNORM   87296u      // 64*4
#define OFF_DFRAG   131072u     // 64*20*4*64*8*2 = 5242880
#define OFF_QFRAG   5373952u    // 64*2*4*64*8*2  = 524288
#define OFF_SIMOUT  5898240u    // 64*64*5*4      = 81920
// total 5980160 bytes

// ---------------------------------------------------------------------------
// Kernel 1: per-doc modality partition (stable), pad segments to x16 by
// DUPLICATING the segment's first token (max-invariant), plus qnorm.
// ---------------------------------------------------------------------------
__global__ void prep_kernel(const int* __restrict__ mod, const int* __restrict__ qmask,
                            int* __restrict__ perm, int* __restrict__ tilemod,
                            int* __restrict__ tcount, float* __restrict__ qnorm) {
    __shared__ int smod[NB * NS];   // 64 KB
    int tid = threadIdx.x;
    for (int i = tid; i < NB * NS; i += 256) smod[i] = mod[i];
    __syncthreads();
    if (tid < NB) {
        int c = tid;
        const int* row = smod + c * NS;
        int pos = 0;
        for (int m = 1; m <= 4; ++m) {
            int start = pos, first = -1;
            for (int s = 0; s < NS; ++s) {
                if (row[s] == m) {
                    if (first < 0) first = s;
                    perm[c * PERMSTRIDE + pos++] = s;
                }
            }
            while (pos & 15) perm[c * PERMSTRIDE + pos++] = first;  // duplicate-pad
            for (int t = (start >> 4); t < (pos >> 4); ++t) tilemod[c * MAXT + t] = m;
        }
        tcount[c] = pos >> 4;
        int cnt = 0;
        for (int q = 0; q < NQ; ++q) cnt += (qmask[c * NQ + q] != 0);
        qnorm[c] = (float)(cnt > 0 ? cnt : 1);
    }
}

// ---------------------------------------------------------------------------
// Kernel 2: query fp32 -> bf16, pre-swizzled into MFMA B-operand frag layout.
// frag[b][qt][kc][lane][j] = q[b][qt*16+(lane&15)][kc*32+(lane>>4)*8+j]
// ---------------------------------------------------------------------------
__global__ void qfrag_kernel(const float* __restrict__ qemb, __bf16* __restrict__ qfrag) {
    int b = blockIdx.x;
    int tid = threadIdx.x;
    int lane = tid & 63, wv = tid >> 6;
    int quad = lane >> 4, li = lane & 15;
    for (int i = 0; i < 2; ++i) {
        int combo = wv * 2 + i;            // 0..7
        int qt = combo >> 2, kc = combo & 3;
        int rowq = qt * 16 + li;
        int k0 = kc * 32 + quad * 8;
        const float* src = qemb + ((size_t)b * NQ + rowq) * ND + k0;
        float4 a = *(const float4*)src;
        float4 bq = *(const float4*)(src + 4);
        bf16x8 o;
        o[0] = (__bf16)a.x;  o[1] = (__bf16)a.y;  o[2] = (__bf16)a.z;  o[3] = (__bf16)a.w;
        o[4] = (__bf16)bq.x; o[5] = (__bf16)bq.y; o[6] = (__bf16)bq.z; o[7] = (__bf16)bq.w;
        *(bf16x8*)(qfrag + (((size_t)(b * 2 + qt) * 4 + kc) * 64 + lane) * 8) = o;
    }
}

// ---------------------------------------------------------------------------
// Kernel 3: doc fp32 -> bf16, permuted by modality partition, pre-swizzled
// into MFMA A-operand frag layout.
// ---------------------------------------------------------------------------
__global__ void dfrag_kernel(const float* __restrict__ demb, const int* __restrict__ perm,
                             const int* __restrict__ tcount, __bf16* __restrict__ dfrag) {
    int c = blockIdx.x;
    int tid = threadIdx.x;
    int lane = tid & 63, kc = tid >> 6;    // wave == kc
    int quad = lane >> 4, li = lane & 15;
    int T = tcount[c];
    int k0 = kc * 32 + quad * 8;
    for (int t = 0; t < T; ++t) {
        int srow = perm[c * PERMSTRIDE + t * 16 + li];
        const float* src = demb + ((size_t)c * NS + srow) * ND + k0;
        float4 a = *(const float4*)src;
        float4 bq = *(const float4*)(src + 4);
        bf16x8 o;
        o[0] = (__bf16)a.x;  o[1] = (__bf16)a.y;  o[2] = (__bf16)a.z;  o[3] = (__bf16)a.w;
        o[4] = (__bf16)bq.x; o[5] = (__bf16)bq.y; o[6] = (__bf16)bq.z; o[7] = (__bf16)bq.w;
        *(bf16x8*)(dfrag + (((size_t)(c * MAXT + t) * 4 + kc) * 64 + lane) * 8) = o;
    }
}

// ---------------------------------------------------------------------------
// Kernel 4: main. One block per (c, b-pair). 4 waves split doc tiles.
// MFMA 16x16x32 bf16: D rows = doc tokens (uniform modality per tile),
// cols = queries. Epilogue: in-lane fold over 4 regs + shfl_xor(16,32),
// then wave-uniform branch on tile modality into vmax[m][qt].
// ---------------------------------------------------------------------------
__global__ __launch_bounds__(256) void
main_kernel(const __bf16* __restrict__ dfrag, const __bf16* __restrict__ qfrag,
            const int* __restrict__ tilemod, const int* __restrict__ tcount,
            const float* __restrict__ qnorm, const int* __restrict__ qmask,
            float* __restrict__ simout) {
    int blk = blockIdx.x;
    int c = blk >> 5;          // 32 consecutive blocks share a doc
    int bp = blk & 31;
    int b0 = bp * 2;
    int tid = threadIdx.x;
    int lane = tid & 63, wv = tid >> 6;

    // hold all q fragments (2 b's x 2 q-tiles x 4 k-chunks) in registers
    bf16x8 bfrag[4][4];
#pragma unroll
    for (int qt = 0; qt < 4; ++qt) {
        int bg = b0 + (qt >> 1), qtl = qt & 1;
#pragma unroll
        for (int kc = 0; kc < 4; ++kc)
            bfrag[qt][kc] = *(const bf16x8*)(qfrag + (((size_t)(bg * 2 + qtl) * 4 + kc) * 64 + lane) * 8);
    }

    float vmax[4][4];
#pragma unroll
    for (int m = 0; m < 4; ++m)
#pragma unroll
        for (int qt = 0; qt < 4; ++qt) vmax[m][qt] = -1e30f;

    int T = tcount[c];
    for (int t = wv; t < T; t += 4) {
        bf16x8 af[4];
#pragma unroll
        for (int kc = 0; kc < 4; ++kc)
            af[kc] = *(const bf16x8*)(dfrag + (((size_t)(c * MAXT + t) * 4 + kc) * 64 + lane) * 8);
        float vv[4];
#pragma unroll
        for (int qt = 0; qt < 4; ++qt) {
            f32x4 acc = {0.f, 0.f, 0.f, 0.f};
#pragma unroll
            for (int kc = 0; kc < 4; ++kc)
                acc = __builtin_amdgcn_mfma_f32_16x16x32_bf16(af[kc], bfrag[qt][kc], acc, 0, 0, 0);
            float v = fmaxf(fmaxf(acc[0], acc[1]), fmaxf(acc[2], acc[3]));
            v = fmaxf(v, __shfl_xor(v, 16, 64));
            v = fmaxf(v, __shfl_xor(v, 32, 64));
            vv[qt] = v;   // tile max for query col (lane&15), all lanes valid
        }
        int tm = tilemod[c * MAXT + t];   // wave-uniform
        switch (tm) {
        case 1:
#pragma unroll
            for (int qt = 0; qt < 4; ++qt) vmax[0][qt] = fmaxf(vmax[0][qt], vv[qt]);
            break;
        case 2:
#pragma unroll
            for (int qt = 0; qt < 4; ++qt) vmax[1][qt] = fmaxf(vmax[1][qt], vv[qt]);
            break;
        case 3:
#pragma unroll
            for (int qt = 0; qt < 4; ++qt) vmax[2][qt] = fmaxf(vmax[2][qt], vv[qt]);
            break;
        default:
#pragma unroll
            for (int qt = 0; qt < 4; ++qt) vmax[3][qt] = fmaxf(vmax[3][qt], vv[qt]);
            break;
        }
    }

    __shared__ float lv[4][4][4][16];   // [wave][m][qt][qi]
    if (lane < 16) {
#pragma unroll
        for (int m = 0; m < 4; ++m)
#pragma unroll
            for (int qt = 0; qt < 4; ++qt) lv[wv][m][qt][lane] = vmax[m][qt];
    }
    __syncthreads();
    __shared__ float l2[4][4][16];      // [m][qt][qi]
    {
        int m = tid >> 6, qt = (tid >> 4) & 3, qi = tid & 15;
        float v = fmaxf(fmaxf(lv[0][m][qt][qi], lv[1][m][qt][qi]),
                        fmaxf(lv[2][m][qt][qi], lv[3][m][qt][qi]));
        l2[m][qt][qi] = v;
    }
    __syncthreads();
    if (tid < 64) {
        int bl = tid >> 5, q = tid & 31;
        int qt = bl * 2 + (q >> 4), qi = q & 15;
        float m1 = l2[0][qt][qi], m2 = l2[1][qt][qi];
        float m3 = l2[2][qt][qi], m4 = l2[3][qt][qi];
        int b = b0 + bl;
        float agg = fmaxf(fmaxf(m1, m2), fmaxf(m3, m4));
        float s0 = (qmask[b * NQ + q] != 0) ? agg : 0.f;
        float s1 = m1, s2 = m2, s3 = m3, s4 = m4;
#pragma unroll
        for (int off = 16; off >= 1; off >>= 1) {
            s0 += __shfl_xor(s0, off, 64);
            s1 += __shfl_xor(s1, off, 64);
            s2 += __shfl_xor(s2, off, 64);
            s3 += __shfl_xor(s3, off, 64);
            s4 += __shfl_xor(s4, off, 64);
        }
        if (q == 0) {
            float inv = 1.f / qnorm[b];
            float* o = simout + ((size_t)b * NB + c) * 5;
            o[0] = s0 * inv; o[1] = s1 * inv; o[2] = s2 * inv;
            o[3] = s3 * inv; o[4] = s4 * inv;
        }
    }
}

// ---------------------------------------------------------------------------
// Kernel 5: per-row two-pass logsumexp over 319 logits, mean over rows.
// Row b multiset: {sim[b,c]: c!=b} U {sims[b,c,m]: all c, m=1..4};
// positive = sims[b,b,query_types[b]] (slot index == query_types[b]).
// ---------------------------------------------------------------------------
__global__ void loss_kernel(const float* __restrict__ simout, const int* __restrict__ qtypes,
                            float* __restrict__ out) {
    __shared__ float lloss[NB];
    int tid = threadIdx.x;
    int r = tid >> 2, i = tid & 3;
    const float invtau = 1.0f / TAU_F;
    float mx = -1e30f;
    for (int cc = 0; cc < 16; ++cc) {
        int c = i * 16 + cc;
        const float* p = simout + ((size_t)r * NB + c) * 5;
#pragma unroll
        for (int j = 0; j < 5; ++j) {
            if (j == 0 && c == r) continue;
            mx = fmaxf(mx, p[j] * invtau);
        }
    }
    mx = fmaxf(mx, __shfl_xor(mx, 1, 64));
    mx = fmaxf(mx, __shfl_xor(mx, 2, 64));
    float sum = 0.f;
    for (int cc = 0; cc < 16; ++cc) {
        int c = i * 16 + cc;
        const float* p = simout + ((size_t)r * NB + c) * 5;
#pragma unroll
        for (int j = 0; j < 5; ++j) {
            if (j == 0 && c == r) continue;
            sum += expf(p[j] * invtau - mx);
        }
    }
    sum += __shfl_xor(sum, 1, 64);
    sum += __shfl_xor(sum, 2, 64);
    if (i == 0) {
        float pos = simout[((size_t)r * NB + r) * 5 + qtypes[r]] * invtau;
        lloss[r] = logf(sum) + mx - pos;
    }
    __syncthreads();
    if (tid == 0) {
        float s = 0.f;
        for (int r2 = 0; r2 < NB; ++r2) s += lloss[r2];
        out[0] = s * (1.0f / NB);
    }
}

// ---------------------------------------------------------------------------
extern "C" void kernel_launch(void* const* d_in, const int* in_sizes, int n_in,
                              void* d_out, int out_size, void* d_ws, size_t ws_size,
                              hipStream_t stream) {
    const float* qemb   = (const float*)d_in[0];
    const float* demb   = (const float*)d_in[1];
    const int*   mod    = (const int*)d_in[2];
    const int*   qtypes = (const int*)d_in[3];
    const int*   qmask  = (const int*)d_in[4];

    char* ws = (char*)d_ws;
    int*    perm    = (int*)(ws + OFF_PERM);
    int*    tilemod = (int*)(ws + OFF_TILEMOD);
    int*    tcount  = (int*)(ws + OFF_TCOUNT);
    float*  qnorm   = (float*)(ws + OFF_QNORM);
    __bf16* dfrag   = (__bf16*)(ws + OFF_DFRAG);
    __bf16* qfrag   = (__bf16*)(ws + OFF_QFRAG);
    float*  simout  = (float*)(ws + OFF_SIMOUT);

    prep_kernel<<<1, 256, 0, stream>>>(mod, qmask, perm, tilemod, tcount, qnorm);
    qfrag_kernel<<<NB, 256, 0, stream>>>(qemb, qfrag);
    dfrag_kernel<<<NB, 256, 0, stream>>>(demb, perm, tcount, dfrag);
    main_kernel<<<2048, 256, 0, stream>>>(dfrag, qfrag, tilemod, tcount, qnorm, qmask, simout);
    loss_kernel<<<1, 256, 0, stream>>>(simout, qtypes, (float*)d_out);
}

// Round 2
// 103.190 us; speedup vs baseline: 2.0182x; 2.0182x over previous
//
#include <hip/hip_runtime.h>
#include <math.h>

#define TAU_F 0.02f
#define NB 64
#define NQ 32
#define NS 256
#define ND 128
#define MAXT 20
#define PERMSTRIDE 320

typedef __bf16 bf16x8 __attribute__((ext_vector_type(8)));
typedef float f32x4 __attribute__((ext_vector_type(4)));

// workspace layout (bytes)
#define OFF_TILEMOD 0u          // 64*20*4 = 5120
#define OFF_TCOUNT  5120u       // 64*4
#define OFF_DFRAG   131072u     // 64*20*4*64*8*2 = 5242880
#define OFF_QFRAG   5373952u    // 64*2*4*64*8*2  = 524288
#define OFF_SIMOUT  5898240u    // 64*64*5*4      = 81920

// ---------------------------------------------------------------------------
// Kernel 1 (fused prep + fragment swizzle).
// Blocks 0..63: doc c — modality partition (stable, pad-to-16 by duplicating
//   the segment's first token; max-invariant), then fp32->bf16 swizzle into
//   MFMA A-operand fragment layout.
// Blocks 64..127: query b — fp32->bf16 swizzle into B-operand fragment layout.
// ---------------------------------------------------------------------------
__global__ __launch_bounds__(256) void
prep_frag_kernel(const float* __restrict__ qemb, const float* __restrict__ demb,
                 const int* __restrict__ mod,
                 __bf16* __restrict__ qfrag, __bf16* __restrict__ dfrag,
                 int* __restrict__ tilemod_g, int* __restrict__ tcount_g) {
    int blk = blockIdx.x;
    int tid = threadIdx.x;
    int lane = tid & 63, wv = tid >> 6;
    int quad = lane >> 4, li = lane & 15;

    if (blk >= NB) {
        // ---- query fragments ----
        int b = blk - NB;
#pragma unroll
        for (int i = 0; i < 2; ++i) {
            int combo = wv * 2 + i;            // 0..7
            int qt = combo >> 2, kc = combo & 3;
            int rowq = qt * 16 + li;
            int k0 = kc * 32 + quad * 8;
            const float* src = qemb + ((size_t)b * NQ + rowq) * ND + k0;
            float4 a = *(const float4*)src;
            float4 bq = *(const float4*)(src + 4);
            bf16x8 o;
            o[0] = (__bf16)a.x;  o[1] = (__bf16)a.y;  o[2] = (__bf16)a.z;  o[3] = (__bf16)a.w;
            o[4] = (__bf16)bq.x; o[5] = (__bf16)bq.y; o[6] = (__bf16)bq.z; o[7] = (__bf16)bq.w;
            *(bf16x8*)(qfrag + (((size_t)(b * 2 + qt) * 4 + kc) * 64 + lane) * 8) = o;
        }
        return;
    }

    // ---- doc partition + fragments ----
    int c = blk;
    __shared__ int smod[NS];
    __shared__ int sperm[PERMSTRIDE];
    __shared__ int counts[5], firsts[5], offs[5], padded[5];
    __shared__ int stilemod[MAXT];
    __shared__ int sT;

    if (tid < 5) { counts[tid] = 0; firsts[tid] = NS; }
    __syncthreads();
    int m_tok = mod[c * NS + tid];
    smod[tid] = m_tok;
    if (m_tok) { atomicAdd(&counts[m_tok], 1); atomicMin(&firsts[m_tok], tid); }
    __syncthreads();
    if (tid == 0) {
        int pos = 0;
        for (int m = 1; m <= 4; ++m) {
            offs[m] = pos;
            int p = (counts[m] + 15) & ~15;
            padded[m] = p;
            for (int t = pos >> 4; t < (pos + p) >> 4; ++t) stilemod[t] = m;
            pos += p;
        }
        sT = pos >> 4;
        tcount_g[c] = pos >> 4;
    }
    __syncthreads();
    // stable rank within modality, scatter into sperm
    if (m_tok) {
        int rank = 0;
        for (int s = 0; s < tid; ++s) rank += (smod[s] == m_tok);
        sperm[offs[m_tok] + rank] = tid;
    }
    // pad slots get the segment's first token (max-invariant duplicate)
    if (tid < 4) {
        int m = tid + 1;
        for (int p = counts[m]; p < padded[m]; ++p) sperm[offs[m] + p] = firsts[m];
    }
    __syncthreads();
    int T = sT;
    if (tid < T) tilemod_g[c * MAXT + tid] = stilemod[tid];

    // fragment swizzle: wave == k-chunk, loop over tiles
    int kc = wv;
    int k0 = kc * 32 + quad * 8;
    for (int t = 0; t < T; ++t) {
        int srow = sperm[t * 16 + li];
        const float* src = demb + ((size_t)c * NS + srow) * ND + k0;
        float4 a = *(const float4*)src;
        float4 bq = *(const float4*)(src + 4);
        bf16x8 o;
        o[0] = (__bf16)a.x;  o[1] = (__bf16)a.y;  o[2] = (__bf16)a.z;  o[3] = (__bf16)a.w;
        o[4] = (__bf16)bq.x; o[5] = (__bf16)bq.y; o[6] = (__bf16)bq.z; o[7] = (__bf16)bq.w;
        *(bf16x8*)(dfrag + (((size_t)(c * MAXT + t) * 4 + kc) * 64 + lane) * 8) = o;
    }
}

// ---------------------------------------------------------------------------
// Kernel 2: main. One block per (c, b-pair). 4 waves split doc tiles.
// MFMA 16x16x32 bf16: D rows = doc tokens (uniform modality per tile),
// cols = queries. Epilogue: in-lane fold over 4 regs + shfl_xor(16,32),
// then wave-uniform branch on tile modality into vmax[m][qt].
// Writes UNNORMALIZED sums (divide by qnorm happens in loss kernel).
// ---------------------------------------------------------------------------
__global__ __launch_bounds__(256) void
main_kernel(const __bf16* __restrict__ dfrag, const __bf16* __restrict__ qfrag,
            const int* __restrict__ tilemod, const int* __restrict__ tcount,
            const int* __restrict__ qmask, float* __restrict__ simout) {
    int blk = blockIdx.x;
    int c = blk >> 5;          // 32 consecutive blocks share a doc
    int bp = blk & 31;
    int b0 = bp * 2;
    int tid = threadIdx.x;
    int lane = tid & 63, wv = tid >> 6;

    // hold all q fragments (2 b's x 2 q-tiles x 4 k-chunks) in registers
    bf16x8 bfrag[4][4];
#pragma unroll
    for (int qt = 0; qt < 4; ++qt) {
        int bg = b0 + (qt >> 1), qtl = qt & 1;
#pragma unroll
        for (int kc = 0; kc < 4; ++kc)
            bfrag[qt][kc] = *(const bf16x8*)(qfrag + (((size_t)(bg * 2 + qtl) * 4 + kc) * 64 + lane) * 8);
    }

    float vmax[4][4];
#pragma unroll
    for (int m = 0; m < 4; ++m)
#pragma unroll
        for (int qt = 0; qt < 4; ++qt) vmax[m][qt] = -1e30f;

    int T = tcount[c];
    for (int t = wv; t < T; t += 4) {
        bf16x8 af[4];
#pragma unroll
        for (int kc = 0; kc < 4; ++kc)
            af[kc] = *(const bf16x8*)(dfrag + (((size_t)(c * MAXT + t) * 4 + kc) * 64 + lane) * 8);
        float vv[4];
#pragma unroll
        for (int qt = 0; qt < 4; ++qt) {
            f32x4 acc = {0.f, 0.f, 0.f, 0.f};
#pragma unroll
            for (int kc = 0; kc < 4; ++kc)
                acc = __builtin_amdgcn_mfma_f32_16x16x32_bf16(af[kc], bfrag[qt][kc], acc, 0, 0, 0);
            float v = fmaxf(fmaxf(acc[0], acc[1]), fmaxf(acc[2], acc[3]));
            v = fmaxf(v, __shfl_xor(v, 16, 64));
            v = fmaxf(v, __shfl_xor(v, 32, 64));
            vv[qt] = v;   // tile max for query col (lane&15), all lanes valid
        }
        int tm = tilemod[c * MAXT + t];   // wave-uniform
        switch (tm) {
        case 1:
#pragma unroll
            for (int qt = 0; qt < 4; ++qt) vmax[0][qt] = fmaxf(vmax[0][qt], vv[qt]);
            break;
        case 2:
#pragma unroll
            for (int qt = 0; qt < 4; ++qt) vmax[1][qt] = fmaxf(vmax[1][qt], vv[qt]);
            break;
        case 3:
#pragma unroll
            for (int qt = 0; qt < 4; ++qt) vmax[2][qt] = fmaxf(vmax[2][qt], vv[qt]);
            break;
        default:
#pragma unroll
            for (int qt = 0; qt < 4; ++qt) vmax[3][qt] = fmaxf(vmax[3][qt], vv[qt]);
            break;
        }
    }

    __shared__ float lv[4][4][4][16];   // [wave][m][qt][qi]
    if (lane < 16) {
#pragma unroll
        for (int m = 0; m < 4; ++m)
#pragma unroll
            for (int qt = 0; qt < 4; ++qt) lv[wv][m][qt][lane] = vmax[m][qt];
    }
    __syncthreads();
    __shared__ float l2[4][4][16];      // [m][qt][qi]
    {
        int m = tid >> 6, qt = (tid >> 4) & 3, qi = tid & 15;
        float v = fmaxf(fmaxf(lv[0][m][qt][qi], lv[1][m][qt][qi]),
                        fmaxf(lv[2][m][qt][qi], lv[3][m][qt][qi]));
        l2[m][qt][qi] = v;
    }
    __syncthreads();
    if (tid < 64) {
        int bl = tid >> 5, q = tid & 31;
        int qt = bl * 2 + (q >> 4), qi = q & 15;
        float m1 = l2[0][qt][qi], m2 = l2[1][qt][qi];
        float m3 = l2[2][qt][qi], m4 = l2[3][qt][qi];
        int b = b0 + bl;
        float agg = fmaxf(fmaxf(m1, m2), fmaxf(m3, m4));
        float s0 = (qmask[b * NQ + q] != 0) ? agg : 0.f;
        float s1 = m1, s2 = m2, s3 = m3, s4 = m4;
#pragma unroll
        for (int off = 16; off >= 1; off >>= 1) {
            s0 += __shfl_xor(s0, off, 64);
            s1 += __shfl_xor(s1, off, 64);
            s2 += __shfl_xor(s2, off, 64);
            s3 += __shfl_xor(s3, off, 64);
            s4 += __shfl_xor(s4, off, 64);
        }
        if (q == 0) {
            float* o = simout + ((size_t)b * NB + c) * 5;
            o[0] = s0; o[1] = s1; o[2] = s2; o[3] = s3; o[4] = s4;
        }
    }
}

// ---------------------------------------------------------------------------
// Kernel 3: per-row two-pass logsumexp over 319 logits, mean over rows.
// Row b multiset: {sim[b,c]: c!=b} U {sims[b,c,m]: all c, m=1..4};
// positive = sims[b,b,query_types[b]] (slot index == query_types[b]).
// Computes qnorm from qmask here (simout is unnormalized).
// ---------------------------------------------------------------------------
__global__ void loss_kernel(const float* __restrict__ simout, const int* __restrict__ qtypes,
                            const int* __restrict__ qmask, float* __restrict__ out) {
    __shared__ float lloss[NB];
    int tid = threadIdx.x;
    int r = tid >> 2, i = tid & 3;
    // qnorm: 4 threads per row each count 8 qmask entries, shfl-sum
    int cnt = 0;
#pragma unroll
    for (int j = 0; j < 8; ++j) cnt += (qmask[r * NQ + i * 8 + j] != 0);
    cnt += __shfl_xor(cnt, 1, 64);
    cnt += __shfl_xor(cnt, 2, 64);
    float scale = 1.0f / (TAU_F * (float)(cnt > 0 ? cnt : 1));

    float mx = -1e30f;
    for (int cc = 0; cc < 16; ++cc) {
        int c = i * 16 + cc;
        const float* p = simout + ((size_t)r * NB + c) * 5;
#pragma unroll
        for (int j = 0; j < 5; ++j) {
            if (j == 0 && c == r) continue;
            mx = fmaxf(mx, p[j] * scale);
        }
    }
    mx = fmaxf(mx, __shfl_xor(mx, 1, 64));
    mx = fmaxf(mx, __shfl_xor(mx, 2, 64));
    float sum = 0.f;
    for (int cc = 0; cc < 16; ++cc) {
        int c = i * 16 + cc;
        const float* p = simout + ((size_t)r * NB + c) * 5;
#pragma unroll
        for (int j = 0; j < 5; ++j) {
            if (j == 0 && c == r) continue;
            sum += expf(p[j] * scale - mx);
        }
    }
    sum += __shfl_xor(sum, 1, 64);
    sum += __shfl_xor(sum, 2, 64);
    if (i == 0) {
        float pos = simout[((size_t)r * NB + r) * 5 + qtypes[r]] * scale;
        lloss[r] = logf(sum) + mx - pos;
    }
    __syncthreads();
    if (tid == 0) {
        float s = 0.f;
        for (int r2 = 0; r2 < NB; ++r2) s += lloss[r2];
        out[0] = s * (1.0f / NB);
    }
}

// ---------------------------------------------------------------------------
extern "C" void kernel_launch(void* const* d_in, const int* in_sizes, int n_in,
                              void* d_out, int out_size, void* d_ws, size_t ws_size,
                              hipStream_t stream) {
    const float* qemb   = (const float*)d_in[0];
    const float* demb   = (const float*)d_in[1];
    const int*   mod    = (const int*)d_in[2];
    const int*   qtypes = (const int*)d_in[3];
    const int*   qmask  = (const int*)d_in[4];

    char* ws = (char*)d_ws;
    int*    tilemod = (int*)(ws + OFF_TILEMOD);
    int*    tcount  = (int*)(ws + OFF_TCOUNT);
    __bf16* dfrag   = (__bf16*)(ws + OFF_DFRAG);
    __bf16* qfrag   = (__bf16*)(ws + OFF_QFRAG);
    float*  simout  = (float*)(ws + OFF_SIMOUT);

    prep_frag_kernel<<<2 * NB, 256, 0, stream>>>(qemb, demb, mod, qfrag, dfrag, tilemod, tcount);
    main_kernel<<<2048, 256, 0, stream>>>(dfrag, qfrag, tilemod, tcount, qmask, simout);
    loss_kernel<<<1, 256, 0, stream>>>(simout, qtypes, qmask, (float*)d_out);
}